// Round 12
// baseline (325.520 us; speedup 1.0000x reference)
//
#include <hip/hip_runtime.h>

#define TPB 256
#define L2E 1.44269504f

typedef float f32x2 __attribute__((ext_vector_type(2)));
typedef float f32x4 __attribute__((ext_vector_type(4)));
typedef short s16x8 __attribute__((ext_vector_type(8)));

// lane->lane XOR shuffle within 32-lane halves (BitMode: xor<<10 | and 0x1F)
#define SWZ(v, m) __int_as_float(__builtin_amdgcn_ds_swizzle(__float_as_int(v), ((m) << 10) | 31))

// DPP cross-lane (VALU): quad_perm xor1/2/3, row_half_mirror = xor7 (within 8)
#define DPP_X1 0xB1
#define DPP_X2 0x4E
#define DPP_X3 0x1B
#define DPP_X7 0x141
template<int CTRL>
__device__ __forceinline__ float DPPX(float v) {
    int i = __float_as_int(v);
    return __int_as_float(__builtin_amdgcn_update_dpp(i, i, CTRL, 0xF, 0xF, false));
}

// packed f32 FMA: acc(2) += w(2)*x(2), one issue slot for 2 MACs (round-3 proven)
#define PKFMA(acc, w, xx) asm("v_pk_fma_f32 %0, %1, %2, %0" : "+v"(acc) : "v"(w), "v"(xx))

// Newton reciprocal (full-rate, replaces quarter-rate v_rcp):
// guess rel-err ~0.1 -> after 2 iters ~1e-4; valid for all normal d >= 1.
__device__ __forceinline__ float rcp_nr(float d) {
    float r = __uint_as_float(0x7EF311C3u - __float_as_uint(d));
    r = r * fmaf(-d, r, 2.0f);
    r = r * fmaf(-d, r, 2.0f);
    return r;
}

// exact two-term bf16 split packed into one u32: low16 = hi-part (even k), high16 = lo-part (odd k)
__device__ __forceinline__ unsigned pack_split(float v) {
    unsigned b  = __float_as_uint(v);
    float    hf = __uint_as_float(b & 0xFFFF0000u);
    unsigned lob = __float_as_uint(v - hf);
    return __builtin_amdgcn_perm(lob, b, 0x07060302u);  // {lob.hi16, b.hi16}
}

// X LDS layout: [t(10)][el(32)][16 words], col XOR-swizzled by ((el&3)<<2) in 4-word chunks
#define XIDX(t, e, col) ((((t) * 32 + (e)) << 4) | ((col) ^ (((e) & 3) << 2)))

// ---------------- prep kernel: build all segment weights once into d_ws ----------------
__global__ void prep_kernel(const float* __restrict__ Wih0,
                            const float* __restrict__ Wih_rest,
                            const float* __restrict__ Whh,
                            const float* __restrict__ bW,
                            unsigned* __restrict__ wsBF,
                            float* __restrict__ wsWH,
                            float* __restrict__ wsBIAS)
{
    const int tid = threadIdx.x;
    for (int seg = 0; seg < 6; ++seg) {
        const int l = seg >> 1, dir = seg & 1;
        {   // B-fragments: frag = nt*2+part; value = dup16(hi/lo of W_scaled[u][d])
            const int lane_ = tid & 63, part = (tid >> 6) & 1, nt = tid >> 7;
            const int u = nt * 16 + (lane_ & 15);
            const float sc = ((u >> 3) == 2) ? (-2.0f * L2E) : (-L2E);
            #pragma unroll
            for (int ip = 0; ip < 4; ++ip) {
                const int d = (lane_ >> 4) * 4 + ip;
                float w;
                if (l == 0) w = (d < 15) ? Wih0[dir * 480 + u * 15 + d] : 0.0f;
                else        w = Wih_rest[((l - 1) * 2 + dir) * 512 + u * 16 + d];
                w *= sc;
                unsigned b = __float_as_uint(w);
                unsigned v16;
                if (part == 0) v16 = b >> 16;
                else {
                    float hf = __uint_as_float(b & 0xFFFF0000u);
                    v16 = __float_as_uint(w - hf) >> 16;
                }
                wsBF[seg * 4096 + ((nt * 2 + part) * 64 + lane_) * 4 + ip] = v16 | (v16 << 16);
            }
        }
        {   // recurrent weights, pre-permuted for XOR exchange: wh[j][g*8+m] = s_g*Whh[g*8+j][j^m]
            const int jj = tid >> 5, rr = tid & 31, g = rr >> 3, m = rr & 7;
            const float sc = (g == 2) ? (-2.0f * L2E) : (-L2E);
            wsWH[seg * 256 + jj * 32 + rr] = sc * Whh[seg * 256 + (g * 8 + jj) * 8 + (jj ^ m)];
        }
        if (tid < 32) {
            const float sc = ((tid >> 3) == 2) ? (-2.0f * L2E) : (-L2E);
            wsBIAS[seg * 32 + tid] = sc * bW[seg * 32 + tid];
        }
    }
}

// one LSTM cell step; gates prescaled so exp2 is direct. whp = 16 f32x2 pairs.
template<bool FIRST>
__device__ __forceinline__ void lstm_step(float gf0, float gf1, float gf2, float gf3,
                                          const f32x2* __restrict__ whp,
                                          float& c, float& h)
{
    float a0, a1, a2, a3;
    if (!FIRST) {
        const float h1 = DPPX<DPP_X1>(h);
        const float h2 = DPPX<DPP_X2>(h);
        const float h3 = DPPX<DPP_X3>(h);
        const float h7 = DPPX<DPP_X7>(h);
        const float h4 = SWZ(h, 4);
        const float h5 = DPPX<DPP_X1>(h4);
        const float h6 = DPPX<DPP_X2>(h4);
        f32x2 hp0 = {h,  h1}, hp1 = {h2, h3}, hp2 = {h4, h5}, hp3 = {h6, h7};
        f32x2 A0 = {gf0, 0.0f}, A1 = {gf1, 0.0f}, A2 = {gf2, 0.0f}, A3 = {gf3, 0.0f};
        PKFMA(A0, whp[0],  hp0); PKFMA(A0, whp[1],  hp1); PKFMA(A0, whp[2],  hp2); PKFMA(A0, whp[3],  hp3);
        PKFMA(A1, whp[4],  hp0); PKFMA(A1, whp[5],  hp1); PKFMA(A1, whp[6],  hp2); PKFMA(A1, whp[7],  hp3);
        PKFMA(A2, whp[8],  hp0); PKFMA(A2, whp[9],  hp1); PKFMA(A2, whp[10], hp2); PKFMA(A2, whp[11], hp3);
        PKFMA(A3, whp[12], hp0); PKFMA(A3, whp[13], hp1); PKFMA(A3, whp[14], hp2); PKFMA(A3, whp[15], hp3);
        a0 = A0.x + A0.y; a1 = A1.x + A1.y; a2 = A2.x + A2.y; a3 = A3.x + A3.y;
    } else {
        a0 = gf0; a1 = gf1; a2 = gf2; a3 = gf3;
    }
    // sigm = rcp(1+exp2(G)), tanh = 2*rcp(1+exp2(G2)) - 1  (rcp via Newton, full-rate)
    const float ig = rcp_nr(1.0f + __builtin_amdgcn_exp2f(a0));
    const float fg = rcp_nr(1.0f + __builtin_amdgcn_exp2f(a1));
    const float gg = fmaf(2.0f, rcp_nr(1.0f + __builtin_amdgcn_exp2f(a2)), -1.0f);
    const float og = rcp_nr(1.0f + __builtin_amdgcn_exp2f(a3));
    c = fmaf(fg, c, ig * gg);
    const float ec = __builtin_amdgcn_exp2f(-2.0f * L2E * c);
    const float th = fmaf(2.0f, rcp_nr(1.0f + ec), -1.0f);
    h = og * th;
}

// ---------------- one direction of one layer, projection fused with the chain ----------------
// DIR=0: tiles m=0..4 ascending (t = 2m, 2m+1).  DIR=1: tiles m=4..0 descending.
template<int DIR, bool LAST>
__device__ __forceinline__ void run_dir(const unsigned* __restrict__ XSin,
                                        unsigned* __restrict__ XSout,
                                        const unsigned* __restrict__ bf,
                                        const float* __restrict__ whg,
                                        const float* __restrict__ biasg,
                                        const float* __restrict__ Wout,
                                        float* __restrict__ g2w,
                                        float& accOut, int lane, int wid)
{
    const int r   = lane & 15;
    const int kb  = lane >> 4;
    const int grp = lane >> 3;
    const int j   = lane & 7;
    const int elg = wid * 8 + grp;

    const int AI0 = (((r >> 3) * 32 + wid * 8 + (r & 7)) << 4) + ((kb ^ (r & 3)) << 2);
    const int sb0 = (kb >> 1) * 256 + r * 8 + (kb & 1) * 4;
    const int gb  = j * 8 + grp;

    s16x8 B0 = *(const s16x8*)&bf[(0 * 64 + lane) * 4];
    s16x8 B1 = *(const s16x8*)&bf[(1 * 64 + lane) * 4];
    s16x8 B2 = *(const s16x8*)&bf[(2 * 64 + lane) * 4];
    s16x8 B3 = *(const s16x8*)&bf[(3 * 64 + lane) * 4];
    const float bs0 = biasg[r], bs1 = biasg[16 + r];

    f32x2 whp[16];
    #pragma unroll
    for (int q = 0; q < 8; ++q) {
        f32x4 t = *(const f32x4*)&whg[j * 32 + q * 4];
        whp[2 * q]     = {t.x, t.y};
        whp[2 * q + 1] = {t.z, t.w};
    }

    float woutr[10];
    if (LAST) {
        #pragma unroll
        for (int t = 0; t < 10; ++t) woutr[t] = Wout[t * 16 + DIR * 8 + j];
    }

    float h = 0.0f, c = 0.0f;
    #pragma unroll
    for (int mi = 0; mi < 5; ++mi) {
        const int m = DIR ? (4 - mi) : mi;
        s16x8 A = *(const s16x8*)&XSin[AI0 + m * 1024];
        f32x4 a0 = {bs0, bs0, bs0, bs0}, a1 = {bs1, bs1, bs1, bs1};
        a0 = __builtin_amdgcn_mfma_f32_16x16x32_bf16(A, B0, a0, 0, 0, 0);
        a0 = __builtin_amdgcn_mfma_f32_16x16x32_bf16(A, B1, a0, 0, 0, 0);
        a1 = __builtin_amdgcn_mfma_f32_16x16x32_bf16(A, B2, a1, 0, 0, 0);
        a1 = __builtin_amdgcn_mfma_f32_16x16x32_bf16(A, B3, a1, 0, 0, 0);
        *(f32x4*)&g2w[sb0]       = a0;   // units 0..15
        *(f32x4*)&g2w[sb0 + 128] = a1;   // units 16..31
        float gf[4][2];
        #pragma unroll
        for (int t2 = 0; t2 < 2; ++t2)
            #pragma unroll
            for (int g = 0; g < 4; ++g)
                gf[g][t2] = g2w[t2 * 256 + g * 64 + gb];

        #pragma unroll
        for (int k = 0; k < 2; ++k) {
            const int t2 = DIR ? (1 - k) : k;      // consume in chain order
            const int s  = 2 * m + t2;
            if (mi == 0 && k == 0)
                lstm_step<true >(gf[0][t2], gf[1][t2], gf[2][t2], gf[3][t2], whp, c, h);
            else
                lstm_step<false>(gf[0][t2], gf[1][t2], gf[2][t2], gf[3][t2], whp, c, h);
            if (LAST) accOut += h * woutr[s];
            else      XSout[XIDX(s, elg, DIR * 8 + j)] = pack_split(h);
        }
    }
}

__global__ __launch_bounds__(TPB, 3)
void lstm_kernel(const float* __restrict__ x,
                 const unsigned* __restrict__ wsBF,
                 const float* __restrict__ wsWH,
                 const float* __restrict__ wsBIAS,
                 const float* __restrict__ Wout,
                 const float* __restrict__ bout,
                 float* __restrict__ out)
{
    __shared__ __align__(16) unsigned XA[5120];   // 20KB
    __shared__ __align__(16) unsigned XB[5120];   // 20KB
    __shared__ __align__(16) float    G2[2048];   // 8KB: 512 f32 per wave

    const int tid  = threadIdx.x;
    const int lane = tid & 63, wid = tid >> 6;

    // per-wave x staging (coalesced: wave reads its own 1200 contiguous floats)
    const float* xw = x + (size_t)blockIdx.x * 4800 + wid * 1200;
    for (int i = lane; i < 1200; i += 64) {
        int e = wid * 8 + i / 150, rr = i % 150;
        int cc = rr / 50, r2 = rr % 50, t = r2 / 5, d = r2 % 5;
        XA[XIDX(t, e, cc * 5 + d)] = pack_split(xw[i]);
    }
    for (int i = lane; i < 80; i += 64) {         // zero col 15 (layer-0 input is 15-dim)
        int t = i >> 3, e = wid * 8 + (i & 7);
        XA[XIDX(t, e, 15)] = 0u;
    }
    // NO __syncthreads anywhere: all LDS regions are wave-private, waves drift freely.

    float* g2w = &G2[wid * 512];
    float accOut = 0.0f;
    // layer 0: XA -> XB
    run_dir<0, false>(XA, XB, wsBF + 0 * 4096, wsWH + 0 * 256, wsBIAS + 0 * 32, Wout, g2w, accOut, lane, wid);
    run_dir<1, false>(XA, XB, wsBF + 1 * 4096, wsWH + 1 * 256, wsBIAS + 1 * 32, Wout, g2w, accOut, lane, wid);
    // layer 1: XB -> XA
    run_dir<0, false>(XB, XA, wsBF + 2 * 4096, wsWH + 2 * 256, wsBIAS + 2 * 32, Wout, g2w, accOut, lane, wid);
    run_dir<1, false>(XB, XA, wsBF + 3 * 4096, wsWH + 3 * 256, wsBIAS + 3 * 32, Wout, g2w, accOut, lane, wid);
    // layer 2: XA -> accOut
    run_dir<0, true >(XA, XB, wsBF + 4 * 4096, wsWH + 4 * 256, wsBIAS + 4 * 32, Wout, g2w, accOut, lane, wid);
    run_dir<1, true >(XA, XB, wsBF + 5 * 4096, wsWH + 5 * 256, wsBIAS + 5 * 32, Wout, g2w, accOut, lane, wid);

    accOut += __shfl_xor(accOut, 1);
    accOut += __shfl_xor(accOut, 2);
    accOut += __shfl_xor(accOut, 4);
    if ((lane & 7) == 0)
        out[(size_t)blockIdx.x * 32 + wid * 8 + (lane >> 3)] = accOut + bout[0];
}

extern "C" void kernel_launch(void* const* d_in, const int* in_sizes, int n_in,
                              void* d_out, int out_size, void* d_ws, size_t ws_size,
                              hipStream_t stream) {
    const float* x        = (const float*)d_in[0];
    const float* Wih0     = (const float*)d_in[1];
    const float* Wih_rest = (const float*)d_in[2];
    const float* Whh      = (const float*)d_in[3];
    const float* b        = (const float*)d_in[4];
    const float* Wout     = (const float*)d_in[5];
    const float* bout     = (const float*)d_in[6];
    float* out = (float*)d_out;

    unsigned* wsBF   = (unsigned*)d_ws;                   // 6*4096 u32 = 96KB
    float*    wsWH   = (float*)d_ws + 6 * 4096;           // 6*256 f32
    float*    wsBIAS = (float*)d_ws + 6 * 4096 + 6 * 256; // 6*32 f32

    prep_kernel<<<1, TPB, 0, stream>>>(Wih0, Wih_rest, Whh, b, wsBF, wsWH, wsBIAS);

    const int nblocks = out_size / 32;  // 8192
    lstm_kernel<<<nblocks, TPB, 0, stream>>>(x, wsBF, wsWH, wsBIAS, Wout, bout, out);
}

// Round 14
// 322.693 us; speedup vs baseline: 1.0088x; 1.0088x over previous
//
#include <hip/hip_runtime.h>

#define TPB 256
#define L2E 1.44269504f

typedef float    f32x4 __attribute__((ext_vector_type(4)));
typedef short    s16x8 __attribute__((ext_vector_type(8)));
typedef unsigned u32;

#define EXP2(x) __builtin_amdgcn_exp2f(x)
#define RCPF(x) __builtin_amdgcn_rcpf(x)

// v_perm_b32 (verified r12): sel bytes 0-3 pick src1 bytes, 4-7 pick src0; little-endian.
__device__ __forceinline__ u32 dup_lo16(u32 x) { return __builtin_amdgcn_perm(x, x, 0x01000100u); } // (lo16,lo16)
__device__ __forceinline__ u32 dup_hi16(u32 x) { return __builtin_amdgcn_perm(x, x, 0x03020302u); } // (hi16,hi16)

// exact two-term bf16 split packed: low16 = hi-part (even k), high16 = lo-part (odd k)
__device__ __forceinline__ u32 pack_split(float v) {
    u32   b  = __float_as_uint(v);
    float hf = __uint_as_float(b & 0xFFFF0000u);
    u32   lb = __float_as_uint(v - hf);
    return __builtin_amdgcn_perm(lb, b, 0x07060302u);   // low16=b.hi16, high16=lb.hi16
}

__device__ __forceinline__ s16x8 as_s16x8(uint4 v) {
    union { uint4 u; s16x8 s; } x; x.u = v; return x.s;
}

// X LDS: per wave [t(10)][el(16)][16 cols] u32 split-packed, col chunks XOR-swizzled by ((el&3)<<2)
#define XIDX(t, e, col) ((((t) * 16 + (e)) << 4) | ((col) ^ (((e) & 3) << 2)))

// ---------------- prep: A-operand weight fragments [seg][frag(4)][lane(64)][4] ----------------
// frag 0/1: Wih grows 0-15 / 16-31 (k=2d,2d+1 = hi,lo of W[grow][d], d=4*kb+ip)
// frag 2/3: Whh grows 0-15 / 16-31 (u=4*kb+ip; u>=8 zero EXCEPT u==15 carries scaled bias)
__global__ void prep_kernel(const float* __restrict__ Wih0,
                            const float* __restrict__ Wih_rest,
                            const float* __restrict__ Whh,
                            const float* __restrict__ bW,
                            u32* __restrict__ wsA)
{
    const int tid = threadIdx.x;
    const int frag = tid >> 6, lane = tid & 63;
    const int r = lane & 15, kb = lane >> 4;
    for (int seg = 0; seg < 6; ++seg) {
        const int l = seg >> 1, dir = seg & 1;
        const int grow = (frag & 1) * 16 + r;
        const float sc = ((grow >> 3) == 2) ? (-2.0f * L2E) : (-L2E);
        #pragma unroll
        for (int ip = 0; ip < 4; ++ip) {
            float w = 0.0f;
            if (frag < 2) {
                const int d = 4 * kb + ip;
                if (l == 0) w = (d < 15) ? Wih0[dir * 480 + grow * 15 + d] : 0.0f;
                else        w = Wih_rest[((l - 1) * 2 + dir) * 512 + grow * 16 + d];
            } else {
                const int u = 4 * kb + ip;
                if (u < 8)        w = Whh[seg * 256 + grow * 8 + u];
                else if (u == 15) w = bW[seg * 32 + grow];   // bias rides k=30,31 vs B=1.0
            }
            w *= sc;
            u32 b = __float_as_uint(w);
            u32 hi = b >> 16;
            float hf = __uint_as_float(b & 0xFFFF0000u);
            u32 lo = __float_as_uint(w - hf) >> 16;
            wsA[seg * 1024 + frag * 256 + lane * 4 + ip] = hi | (lo << 16);
        }
    }
}

// ---------------- one bidirectional layer, MFMA recurrence, 16 elements per wave ----------------
template<bool LAST>
__device__ __forceinline__ void run_layer(u32* __restrict__ Xw,
                                          const u32* __restrict__ wsSeg,  // F base; B at +1024
                                          const float* __restrict__ sw,
                                          float& accOut, int lane)
{
    const int el = lane & 15, p = lane >> 4;
    const bool pl = (lane < 32);   // quadrants 0,1: own {i,g}; quadrants 2,3: own {f,o}

    // stationary A-frags (weights)
    s16x8 AWxF0 = as_s16x8(*(const uint4*)&wsSeg[0 * 256 + lane * 4]);
    s16x8 AWxF1 = as_s16x8(*(const uint4*)&wsSeg[1 * 256 + lane * 4]);
    s16x8 AWhF0 = as_s16x8(*(const uint4*)&wsSeg[2 * 256 + lane * 4]);
    s16x8 AWhF1 = as_s16x8(*(const uint4*)&wsSeg[3 * 256 + lane * 4]);
    s16x8 AWxB0 = as_s16x8(*(const uint4*)&wsSeg[1024 + 0 * 256 + lane * 4]);
    s16x8 AWxB1 = as_s16x8(*(const uint4*)&wsSeg[1024 + 1 * 256 + lane * 4]);
    s16x8 AWhB0 = as_s16x8(*(const uint4*)&wsSeg[1024 + 2 * 256 + lane * 4]);
    s16x8 AWhB1 = as_s16x8(*(const uint4*)&wsSeg[1024 + 3 * 256 + lane * 4]);

    const u32 M   = pl ? 0xFFFFFFFFu : 0u;          // Bh zero for kb>=2 (Whh rows u>=8)
    const u32 PAD = (p == 3) ? 0x3F803F80u : 0u;    // B=1.0(bf16) at k=30,31 -> bias
    const float tA = pl ? 2.0f : 1.0f;              // acc1: p<2 tanh-map (2t-1), p>=2 sigm (t)
    const float tB = pl ? -1.0f : 0.0f;

    float cF[4] = {0,0,0,0}, cB[4] = {0,0,0,0};
    float hF[4] = {0,0,0,0}, hB[4] = {0,0,0,0};
    u32 hist[10][4];

    #pragma unroll
    for (int tt = 0; tt < 10; ++tt) {
        const int tF = tt, tBk = 9 - tt;
        uint4 xF = *(const uint4*)&Xw[XIDX(tF,  el, 4 * p)];
        uint4 xB = *(const uint4*)&Xw[XIDX(tBk, el, 4 * p)];

        // data B-frags: dup(hi) and dup(lo)
        uint4 BxFhi = {dup_lo16(xF.x), dup_lo16(xF.y), dup_lo16(xF.z), dup_lo16(xF.w)};
        uint4 BxFlo = {dup_hi16(xF.x), dup_hi16(xF.y), dup_hi16(xF.z), dup_hi16(xF.w)};
        uint4 BxBhi = {dup_lo16(xB.x), dup_lo16(xB.y), dup_lo16(xB.z), dup_lo16(xB.w)};
        uint4 BxBlo = {dup_hi16(xB.x), dup_hi16(xB.y), dup_hi16(xB.z), dup_hi16(xB.w)};

        uint4 BhFhi, BhFlo, BhBhi, BhBlo;
        {
            u32* fh = (u32*)&BhFhi; u32* fl = (u32*)&BhFlo;
            u32* bh = (u32*)&BhBhi; u32* bl = (u32*)&BhBlo;
            #pragma unroll
            for (int q = 0; q < 4; ++q) {
                u32 hb = __float_as_uint(hF[q]);
                float lo = hF[q] - __uint_as_float(hb & 0xFFFF0000u);
                fh[q] = dup_hi16(hb) & M;
                fl[q] = dup_hi16(__float_as_uint(lo)) & M;
                u32 hb2 = __float_as_uint(hB[q]);
                float lo2 = hB[q] - __uint_as_float(hb2 & 0xFFFF0000u);
                bh[q] = dup_hi16(hb2) & M;
                bl[q] = dup_hi16(__float_as_uint(lo2)) & M;
            }
            fh[3] |= PAD;  bh[3] |= PAD;
        }

        f32x4 z = {0,0,0,0};
        f32x4 aF0 = z, aF1 = z, aB0 = z, aB1 = z;
        aF0 = __builtin_amdgcn_mfma_f32_16x16x32_bf16(AWxF0, as_s16x8(BxFhi), aF0, 0,0,0);
        aF0 = __builtin_amdgcn_mfma_f32_16x16x32_bf16(AWxF0, as_s16x8(BxFlo), aF0, 0,0,0);
        aF0 = __builtin_amdgcn_mfma_f32_16x16x32_bf16(AWhF0, as_s16x8(BhFhi), aF0, 0,0,0);
        aF0 = __builtin_amdgcn_mfma_f32_16x16x32_bf16(AWhF0, as_s16x8(BhFlo), aF0, 0,0,0);
        aF1 = __builtin_amdgcn_mfma_f32_16x16x32_bf16(AWxF1, as_s16x8(BxFhi), aF1, 0,0,0);
        aF1 = __builtin_amdgcn_mfma_f32_16x16x32_bf16(AWxF1, as_s16x8(BxFlo), aF1, 0,0,0);
        aF1 = __builtin_amdgcn_mfma_f32_16x16x32_bf16(AWhF1, as_s16x8(BhFhi), aF1, 0,0,0);
        aF1 = __builtin_amdgcn_mfma_f32_16x16x32_bf16(AWhF1, as_s16x8(BhFlo), aF1, 0,0,0);
        aB0 = __builtin_amdgcn_mfma_f32_16x16x32_bf16(AWxB0, as_s16x8(BxBhi), aB0, 0,0,0);
        aB0 = __builtin_amdgcn_mfma_f32_16x16x32_bf16(AWxB0, as_s16x8(BxBlo), aB0, 0,0,0);
        aB0 = __builtin_amdgcn_mfma_f32_16x16x32_bf16(AWhB0, as_s16x8(BhBhi), aB0, 0,0,0);
        aB0 = __builtin_amdgcn_mfma_f32_16x16x32_bf16(AWhB0, as_s16x8(BhBlo), aB0, 0,0,0);
        aB1 = __builtin_amdgcn_mfma_f32_16x16x32_bf16(AWxB1, as_s16x8(BxBhi), aB1, 0,0,0);
        aB1 = __builtin_amdgcn_mfma_f32_16x16x32_bf16(AWxB1, as_s16x8(BxBlo), aB1, 0,0,0);
        aB1 = __builtin_amdgcn_mfma_f32_16x16x32_bf16(AWhB1, as_s16x8(BhBhi), aB1, 0,0,0);
        aB1 = __builtin_amdgcn_mfma_f32_16x16x32_bf16(AWhB1, as_s16x8(BhBlo), aB1, 0,0,0);

        // gates: acc0 -> sigm (i for p<2, f for p>=2); acc1 -> tanh (g) / sigm (o)
        float sF0[4], vF1[4], sB0[4], vB1[4];
        #pragma unroll
        for (int q = 0; q < 4; ++q) {
            sF0[q] = RCPF(1.0f + EXP2(aF0[q]));
            vF1[q] = fmaf(tA, RCPF(1.0f + EXP2(aF1[q])), tB);
            sB0[q] = RCPF(1.0f + EXP2(aB0[q]));
            vB1[q] = fmaf(tA, RCPF(1.0f + EXP2(aB1[q])), tB);
        }
        // exchange with the partner quadrant (p0<->p2, p1<->p3 == lane^32)
        #pragma unroll
        for (int q = 0; q < 4; ++q) {
            const float wF0 = __shfl_xor(sF0[q], 32);
            const float wF1 = __shfl_xor(vF1[q], 32);
            const float iF = pl ? sF0[q] : wF0;
            const float gF = pl ? vF1[q] : wF1;
            const float fF = pl ? wF0 : sF0[q];
            const float oF = pl ? wF1 : vF1[q];
            cF[q] = fmaf(fF, cF[q], iF * gF);
            const float eF = EXP2(-2.0f * L2E * cF[q]);
            hF[q] = oF * fmaf(2.0f, RCPF(1.0f + eF), -1.0f);

            const float wB0 = __shfl_xor(sB0[q], 32);
            const float wB1 = __shfl_xor(vB1[q], 32);
            const float iB = pl ? sB0[q] : wB0;
            const float gB = pl ? vB1[q] : wB1;
            const float fB = pl ? wB0 : sB0[q];
            const float oB = pl ? wB1 : vB1[q];
            cB[q] = fmaf(fB, cB[q], iB * gB);
            const float eB = EXP2(-2.0f * L2E * cB[q]);
            hB[q] = oB * fmaf(2.0f, RCPF(1.0f + eB), -1.0f);
        }

        if (LAST) {
            const int tSel = pl ? tF : tBk;
            f32x4 wv = *(const f32x4*)&sw[tSel * 16 + 4 * p];
            #pragma unroll
            for (int q = 0; q < 4; ++q)
                accOut = fmaf(pl ? hF[q] : hB[q], wv[q], accOut);
        } else {
            #pragma unroll
            for (int q = 0; q < 4; ++q)
                hist[tt][q] = pack_split(pl ? hF[q] : hB[q]);
        }
    }

    if (!LAST) {
        // all 20 x-reads are done; bulk-write h (each lane owns distinct cols 4p..4p+3).
        // fwd lanes: hist[tt] is h_fwd[tt] -> row tt.
        // bwd lanes: hist[tt] is h_bwd[9-tt] -> row 9-tt  (r13 BUG FIX: was written to row tt)
        #pragma unroll
        for (int t = 0; t < 10; ++t) {
            const int t_eff = pl ? t : (9 - t);
            uint4 v = {hist[t][0], hist[t][1], hist[t][2], hist[t][3]};
            *(uint4*)&Xw[XIDX(t_eff, el, 4 * p)] = v;
        }
    }
}

__global__ __launch_bounds__(TPB, 3)
void lstm_kernel(const float* __restrict__ x,
                 const u32* __restrict__ wsA,
                 const float* __restrict__ Wout,
                 const float* __restrict__ bout,
                 float* __restrict__ out)
{
    __shared__ __align__(16) u32   XL[4 * 2560];    // 40KB: per-wave [10][16][16]
    __shared__ __align__(16) float SWOUT[4 * 160];  // per-wave Wout copy (no barriers needed)

    const int tid  = threadIdx.x;
    const int lane = tid & 63, wid = tid >> 6;
    u32*   Xw = XL + wid * 2560;
    float* sw = SWOUT + wid * 160;

    for (int i = lane; i < 160; i += 64) sw[i] = Wout[i];

    // stage x (wave-private 16 elements, coalesced within the wave's 2400-float span)
    const float* xw = x + (size_t)blockIdx.x * (64 * 150) + wid * (16 * 150);
    for (int i = lane; i < 2400; i += 64) {
        int e = i / 150, rr = i % 150;
        int c = rr / 50, r2 = rr % 50, t = r2 / 5, d = r2 % 5;
        Xw[XIDX(t, e, c * 5 + d)] = pack_split(xw[i]);
    }
    for (int i = lane; i < 160; i += 64) {
        int t = i >> 4, e = i & 15;
        Xw[XIDX(t, e, 15)] = 0u;
    }
    // NO __syncthreads anywhere: everything is wave-private.

    float accOut = 0.0f;
    run_layer<false>(Xw, wsA + 0 * 2048, sw, accOut, lane);
    run_layer<false>(Xw, wsA + 1 * 2048, sw, accOut, lane);
    run_layer<true >(Xw, wsA + 2 * 2048, sw, accOut, lane);

    // sum quadrant contributions (p0..p3) per element
    accOut += __shfl_xor(accOut, 16);
    accOut += __shfl_xor(accOut, 32);
    if (lane < 16)
        out[(size_t)blockIdx.x * 64 + wid * 16 + lane] = accOut + bout[0];
}

extern "C" void kernel_launch(void* const* d_in, const int* in_sizes, int n_in,
                              void* d_out, int out_size, void* d_ws, size_t ws_size,
                              hipStream_t stream) {
    const float* x        = (const float*)d_in[0];
    const float* Wih0     = (const float*)d_in[1];
    const float* Wih_rest = (const float*)d_in[2];
    const float* Whh      = (const float*)d_in[3];
    const float* b        = (const float*)d_in[4];
    const float* Wout     = (const float*)d_in[5];
    const float* bout     = (const float*)d_in[6];
    float* out = (float*)d_out;

    u32* wsA = (u32*)d_ws;   // 6 segs * 1024 u32 = 24KB

    prep_kernel<<<1, TPB, 0, stream>>>(Wih0, Wih_rest, Whh, b, wsA);

    const int nblocks = out_size / 64;   // 4096
    lstm_kernel<<<nblocks, TPB, 0, stream>>>(x, wsA, Wout, bout, out);
}